// Round 7
// baseline (110.426 us; speedup 1.0000x reference)
//
#include <hip/hip_runtime.h>
#include <math.h>

#define LAM 0.01f

typedef __bf16 bf16x8 __attribute__((ext_vector_type(8)));
typedef float f32x4 __attribute__((ext_vector_type(4)));
typedef short short8v __attribute__((ext_vector_type(8)));

#define BF(v) __builtin_bit_cast(bf16x8, (v))
#define MFMA __builtin_amdgcn_mfma_f32_16x16x32_bf16

__device__ __forceinline__ unsigned short f2bf(float f) {
    __bf16 h = (__bf16)f;
    return __builtin_bit_cast(unsigned short, h);
}
__device__ __forceinline__ float bf2f(unsigned short u) {
    unsigned int v = ((unsigned int)u) << 16;
    return __builtin_bit_cast(float, v);
}

// wave task id tau in [0,120): P, chunk-of-16-freqs, t-segment, jump target.
// sh = 9 - log2(P); all twiddle indices live in 512-space (angle 2*pi*m/512).
struct Task { int sh, c16, t_lo, t_hi, jump_s; };
__device__ __forceinline__ Task task_params(int tau) {
    Task tk;
    if (tau < 64)        { int seg = tau >> 4; tk.sh = 1; tk.c16 = tau & 15;
                           tk.t_lo = 127 + 32 * seg; tk.t_hi = tk.t_lo + 31; tk.jump_s = tk.t_lo + 1; }  // P=256
    else if (tau < 96)   { tk.sh = 0; tk.c16 = tau - 64; tk.t_lo = 255; tk.t_hi = 255; tk.jump_s = 256; } // P=512
    else if (tau < 112)  { int u = tau - 96; int seg = u >> 3; tk.sh = 2; tk.c16 = u & 7;
                           tk.t_lo = 63 + 32 * seg; tk.t_hi = tk.t_lo + 31; tk.jump_s = tk.t_lo + 1; }    // P=128
    else if (tau < 116)  { tk.sh = 3; tk.c16 = tau - 112; tk.t_lo = 31; tk.t_hi = 62; tk.jump_s = 32; }   // P=64
    else if (tau < 118)  { tk.sh = 4; tk.c16 = tau - 116; tk.t_lo = 15; tk.t_hi = 30; tk.jump_s = 0; }    // P=32
    else if (tau == 118) { tk.sh = 5; tk.c16 = 0; tk.t_lo = 7; tk.t_hi = 14; tk.jump_s = 0; }             // P=16
    else                 { tk.sh = 6; tk.c16 = 0; tk.t_lo = 0; tk.t_hi = 6;  tk.jump_s = 0; }             // P=8
    return tk;
}

// MFMA layouts (m89-verified convention):
//  A: row = lane&15, k = (lane>>4)*8 + j  |  B: k = (lane>>4)*8 + j, col = lane&15
//  C/D: col = lane&15, row = (lane>>4)*4 + reg
__global__ __launch_bounds__(256, 4)
void afno_mfma(const float* __restrict__ x,
               const float* __restrict__ w1,
               const float* __restrict__ b1,
               const float* __restrict__ w2,
               const float* __restrict__ b2,
               float* __restrict__ out) {
    __shared__ unsigned short xs[8192];     // raw bf16 x, [rows<=256][32]        16 KB
    __shared__ float2 tw[544];              // padded twiddles (idx m + (m>>4))   4.25 KB
    __shared__ unsigned short tbuf[5120];   // per-wave slab, 4 x 2560 B          10 KB

    int bid = blockIdx.x;
    int w  = bid >> 5;          // 0..29 task-slot (heavy slots dispatched first)
    int bn = bid & 31;
    int b = bn >> 3, n = bn & 7;

    int tid = threadIdx.x;
    int wv = tid >> 6;
    int lane = tid & 63;
    int lg = lane >> 4;
    int l15 = lane & 15;
    int krow = lg * 8;

    // ---- stage x rows (raw bf16) ----
    int rows = 0;
    #pragma unroll
    for (int q = 0; q < 4; ++q) {
        Task t2 = task_params((w << 2) | q);
        rows = rows > (t2.t_hi + 1) ? rows : (t2.t_hi + 1);
    }
    for (int idx = tid; idx < rows * 16; idx += 256) {
        int row = idx >> 4, cp = idx & 15;
        float2 v = *(const float2*)(x + (b * 256 + row) * 256 + n * 32 + cp * 2);
        unsigned int pk = (unsigned int)f2bf(v.x) | ((unsigned int)f2bf(v.y) << 16);
        *(unsigned int*)(xs + idx * 2) = pk;
    }
    for (int m = tid; m < 512; m += 256) {
        float sv, cv;
        sincosf(6.28318530717958647692f * (float)m * (1.0f / 512.0f), &sv, &cv);
        tw[m + (m >> 4)] = make_float2(cv, sv);
    }

    Task tk = task_params((w << 2) | wv);
    int P = 512 >> tk.sh;
    float invSqrtP = rsqrtf((float)P);

    // ---- weights -> bf16 B-fragments; W1 carries the forward 1/sqrt(P) ----
    const float* w1r = w1 + n * 1024;
    const float* w1i = w1 + (8 + n) * 1024;
    const float* w2r = w2 + n * 1024;
    const float* w2i = w2 + (8 + n) * 1024;
    short8v W10[2], W11[2], W20[2], W21[2];
    float b1r_[2], b1i_[2], b2r_[2], b2i_[2];
    #pragma unroll
    for (int h = 0; h < 2; ++h) {
        int col = h * 16 + l15;
        #pragma unroll
        for (int j = 0; j < 8; ++j) {
            W10[h][j] = (short)f2bf(w1r[(krow + j) * 32 + col] * invSqrtP);
            W11[h][j] = (short)f2bf(w1i[(krow + j) * 32 + col] * invSqrtP);
            W20[h][j] = (short)f2bf(w2r[(krow + j) * 32 + col]);
            W21[h][j] = (short)f2bf(w2i[(krow + j) * 32 + col]);
        }
        b1r_[h] = b1[n * 32 + col];
        b1i_[h] = b1[(8 + n) * 32 + col];
        b2r_[h] = b2[n * 32 + col];
        b2i_[h] = b2[(8 + n) * 32 + col];
    }
    __syncthreads();   // only block barrier

    int cbase = tk.c16 * 16;
    int pA5 = ((cbase + l15) << tk.sh) & 511;
    int prow5[4];
    #pragma unroll
    for (int r = 0; r < 4; ++r) prow5[r] = ((cbase + lg * 4 + r) << tk.sh) & 511;

    unsigned short* slab = tbuf + wv * 1280;   // [R:16x40][I:16x40] bf16
    int prl = ((l15 & 3) << 2) | (l15 >> 2);   // row involution for bank spread
    const short8v* rpR = (const short8v*)(slab + prl * 40 + krow);
    const short8v* rpI = (const short8v*)(slab + 640 + prl * 40 + krow);

    float Xre[8] = {0,0,0,0,0,0,0,0}, Xim[8] = {0,0,0,0,0,0,0,0};
    int mA5 = 0;
    bool jumped = tk.jump_s > 0;

    if (jumped) {
        // ---- prefix jump: X = sum_{s<jump_s} e^{-i th} x[s] via MFMA (raw) ----
        f32x4 jre0 = {0,0,0,0}, jre1 = {0,0,0,0}, jim0 = {0,0,0,0}, jim1 = {0,0,0,0};
        int nkk = tk.jump_s >> 5;
        for (int kk = 0; kk < nkk; ++kk) {
            int sb = kk * 32;
            int mj = (pA5 * (sb + krow)) & 511;
            short8v ac, an_;
            #pragma unroll
            for (int j = 0; j < 8; ++j) {
                float2 t = tw[mj + (mj >> 4)];
                mj = (mj + pA5) & 511;
                ac[j]  = (short)f2bf(t.x);
                an_[j] = (short)f2bf(-t.y);
            }
            short8v bx0, bx1;
            #pragma unroll
            for (int j = 0; j < 8; ++j) {
                int base = (sb + krow + j) * 32 + l15;
                bx0[j] = (short)xs[base];
                bx1[j] = (short)xs[base + 16];
            }
            jre0 = MFMA(BF(ac),  BF(bx0), jre0, 0, 0, 0);
            jim0 = MFMA(BF(an_), BF(bx0), jim0, 0, 0, 0);
            jre1 = MFMA(BF(ac),  BF(bx1), jre1, 0, 0, 0);
            jim1 = MFMA(BF(an_), BF(bx1), jim1, 0, 0, 0);
        }
        // C->A transpose through slab, two f32 passes ([16][33] = 2112B <= 2560B)
        float* jt = (float*)slab;
        #pragma unroll
        for (int r = 0; r < 4; ++r) {
            jt[(lg * 4 + r) * 33 + l15]      = jre0[r];
            jt[(lg * 4 + r) * 33 + 16 + l15] = jre1[r];
        }
        asm volatile("s_waitcnt lgkmcnt(0)" ::: "memory");
        __builtin_amdgcn_sched_barrier(0);
        #pragma unroll
        for (int j = 0; j < 8; ++j) Xre[j] = jt[l15 * 33 + krow + j];
        asm volatile("s_waitcnt lgkmcnt(0)" ::: "memory");
        __builtin_amdgcn_sched_barrier(0);
        #pragma unroll
        for (int r = 0; r < 4; ++r) {
            jt[(lg * 4 + r) * 33 + l15]      = jim0[r];
            jt[(lg * 4 + r) * 33 + 16 + l15] = jim1[r];
        }
        asm volatile("s_waitcnt lgkmcnt(0)" ::: "memory");
        __builtin_amdgcn_sched_barrier(0);
        #pragma unroll
        for (int j = 0; j < 8; ++j) Xim[j] = jt[l15 * 33 + krow + j];
        mA5 = (pA5 * tk.jump_s) & 511;
    } else {
        // small-P incremental prefix (<=15 steps)
        for (int s = 0; s < tk.t_lo; ++s) {
            int mi = mA5 + (mA5 >> 4);
            float2 tA = tw[mi];
            mA5 = (mA5 + pA5) & 511;
            short8v xv8 = *(const short8v*)(xs + s * 32 + krow);
            #pragma unroll
            for (int j = 0; j < 8; ++j) {
                float xf = bf2f((unsigned short)xv8[j]);
                Xre[j] = fmaf(xf, tA.x, Xre[j]);
                Xim[j] = fmaf(xf, -tA.y, Xim[j]);
            }
        }
    }

    int mrow5[4];
    #pragma unroll
    for (int r = 0; r < 4; ++r) mrow5[r] = (prow5[r] * tk.t_lo) & 511;

    for (int s = tk.t_lo; s <= tk.t_hi; ++s) {
        if (!(jumped && s == tk.t_lo)) {
            int mi = mA5 + (mA5 >> 4);
            float2 tA = tw[mi];
            mA5 = (mA5 + pA5) & 511;
            short8v xv8 = *(const short8v*)(xs + s * 32 + krow);
            #pragma unroll
            for (int j = 0; j < 8; ++j) {
                float xf = bf2f((unsigned short)xv8[j]);
                Xre[j] = fmaf(xf, tA.x, Xre[j]);
                Xim[j] = fmaf(xf, -tA.y, Xim[j]);
            }
        }
        short8v ars, ais, ans;
        #pragma unroll
        for (int j = 0; j < 8; ++j) {
            ars[j] = (short)f2bf(Xre[j]);
            ais[j] = (short)f2bf(Xim[j]);
            ans[j] = ais[j] ^ (short)0x8000;
        }
        // layer 1 (bias in accumulator init)
        f32x4 o1r[2], o1i[2];
        #pragma unroll
        for (int h = 0; h < 2; ++h) {
            f32x4 cr = {b1r_[h], b1r_[h], b1r_[h], b1r_[h]};
            f32x4 ci = {b1i_[h], b1i_[h], b1i_[h], b1i_[h]};
            o1r[h] = MFMA(BF(ars), BF(W10[h]), cr, 0, 0, 0);
            o1r[h] = MFMA(BF(ans), BF(W11[h]), o1r[h], 0, 0, 0);
            o1i[h] = MFMA(BF(ais), BF(W10[h]), ci, 0, 0, 0);
            o1i[h] = MFMA(BF(ars), BF(W11[h]), o1i[h], 0, 0, 0);
        }
        // relu + C->A transpose (permuted rows: logical lg*4+r at phys r*4+lg)
        asm volatile("s_waitcnt lgkmcnt(0)" ::: "memory");   // WAR vs prev reads
        __builtin_amdgcn_sched_barrier(0);
        #pragma unroll
        for (int h = 0; h < 2; ++h) {
            #pragma unroll
            for (int r = 0; r < 4; ++r) {
                slab[(r * 4 + lg) * 40 + h * 16 + l15]       = f2bf(fmaxf(o1r[h][r], 0.f));
                slab[640 + (r * 4 + lg) * 40 + h * 16 + l15] = f2bf(fmaxf(o1i[h][r], 0.f));
            }
        }
        asm volatile("s_waitcnt lgkmcnt(0)" ::: "memory");
        __builtin_amdgcn_sched_barrier(0);
        short8v a2r = *rpR;
        short8v a2i = *rpI;
        short8v a2n;
        #pragma unroll
        for (int j = 0; j < 8; ++j) a2n[j] = a2i[j] ^ (short)0x8000;

        // layer 2
        f32x4 o2r[2], o2i[2];
        #pragma unroll
        for (int h = 0; h < 2; ++h) {
            f32x4 cr = {b2r_[h], b2r_[h], b2r_[h], b2r_[h]};
            f32x4 ci = {b2i_[h], b2i_[h], b2i_[h], b2i_[h]};
            o2r[h] = MFMA(BF(a2r), BF(W20[h]), cr, 0, 0, 0);
            o2r[h] = MFMA(BF(a2n), BF(W21[h]), o2r[h], 0, 0, 0);
            o2i[h] = MFMA(BF(a2i), BF(W20[h]), ci, 0, 0, 0);
            o2i[h] = MFMA(BF(a2r), BF(W21[h]), o2i[h], 0, 0, 0);
        }

        // softshrink + inverse twiddle + row-reduce + atomic
        float sh0 = 0.f, sh1 = 0.f;
        #pragma unroll
        for (int r = 0; r < 4; ++r) {
            int mi = mrow5[r] + (mrow5[r] >> 4);
            float2 tR = tw[mi];
            mrow5[r] = (mrow5[r] + prow5[r]) & 511;
            float v0r = o2r[0][r]; v0r -= __builtin_amdgcn_fmed3f(v0r, -LAM, LAM);
            float v0i = o2i[0][r]; v0i -= __builtin_amdgcn_fmed3f(v0i, -LAM, LAM);
            sh0 = fmaf(v0r, tR.x, sh0); sh0 = fmaf(-v0i, tR.y, sh0);
            float v1r = o2r[1][r]; v1r -= __builtin_amdgcn_fmed3f(v1r, -LAM, LAM);
            float v1i = o2i[1][r]; v1i -= __builtin_amdgcn_fmed3f(v1i, -LAM, LAM);
            sh1 = fmaf(v1r, tR.x, sh1); sh1 = fmaf(-v1i, tR.y, sh1);
        }
        sh0 += __shfl_xor(sh0, 16);
        sh1 += __shfl_xor(sh1, 16);
        if (P > 8) {             // P=8: rows 8..15 alias freqs 0..7 -> exclude
            sh0 += __shfl_xor(sh0, 32);
            sh1 += __shfl_xor(sh1, 32);
        }
        float vsel = (lane & 16) ? sh1 : sh0;
        if (lane < 32)
            atomicAdd(out + (b * 256 + s) * 256 + n * 32 + (lane & 31), vsel * invSqrtP);
    }
}

extern "C" void kernel_launch(void* const* d_in, const int* in_sizes, int n_in,
                              void* d_out, int out_size, void* d_ws, size_t ws_size,
                              hipStream_t stream) {
    const float* x  = (const float*)d_in[0];
    const float* w1 = (const float*)d_in[1];
    const float* b1 = (const float*)d_in[2];
    const float* w2 = (const float*)d_in[3];
    const float* b2 = (const float*)d_in[4];
    float* out = (float*)d_out;

    // out = x (the "+ x" residual), then the main kernel atomically accumulates.
    hipMemcpyAsync(out, x, (size_t)(4 * 256 * 256) * sizeof(float),
                   hipMemcpyDeviceToDevice, stream);
    hipLaunchKernelGGL(afno_mfma, dim3(960), dim3(256), 0, stream,
                       x, w1, b1, w2, b2, out);
}

// Round 8
// 97.569 us; speedup vs baseline: 1.1318x; 1.1318x over previous
//
#include <hip/hip_runtime.h>
#include <math.h>

#define LAM 0.01f

typedef __bf16 bf16x8 __attribute__((ext_vector_type(8)));
typedef float f32x4 __attribute__((ext_vector_type(4)));
typedef short short8v __attribute__((ext_vector_type(8)));

#define BF(v) __builtin_bit_cast(bf16x8, (v))
#define MFMA __builtin_amdgcn_mfma_f32_16x16x32_bf16
#define LDS_FENCE() do { asm volatile("s_waitcnt lgkmcnt(0)" ::: "memory"); \
                         __builtin_amdgcn_sched_barrier(0); } while (0)

__device__ __forceinline__ unsigned short f2bf(float f) {
    __bf16 h = (__bf16)f;
    return __builtin_bit_cast(unsigned short, h);
}
__device__ __forceinline__ float bf2f(unsigned short u) {
    unsigned int v = ((unsigned int)u) << 16;
    return __builtin_bit_cast(float, v);
}

// wave task id tau in [0,120): P, chunk-of-16-freqs, t-segment, jump target.
// sh = 9 - log2(P); twiddle indices in 512-space (angle 2*pi*m/512).
struct Task { int sh, c16, t_lo, t_hi, jump_s; };
__device__ __forceinline__ Task task_params(int tau) {
    Task tk;
    if (tau < 64)        { int seg = tau >> 4; tk.sh = 1; tk.c16 = tau & 15;
                           tk.t_lo = 127 + 32 * seg; tk.t_hi = tk.t_lo + 31; tk.jump_s = tk.t_lo + 1; }  // P=256
    else if (tau < 96)   { tk.sh = 0; tk.c16 = tau - 64; tk.t_lo = 255; tk.t_hi = 255; tk.jump_s = 256; } // P=512
    else if (tau < 112)  { int u = tau - 96; int seg = u >> 3; tk.sh = 2; tk.c16 = u & 7;
                           tk.t_lo = 63 + 32 * seg; tk.t_hi = tk.t_lo + 31; tk.jump_s = tk.t_lo + 1; }    // P=128
    else if (tau < 116)  { tk.sh = 3; tk.c16 = tau - 112; tk.t_lo = 31; tk.t_hi = 62; tk.jump_s = 32; }   // P=64
    else if (tau < 118)  { tk.sh = 4; tk.c16 = tau - 116; tk.t_lo = 15; tk.t_hi = 30; tk.jump_s = 0; }    // P=32
    else if (tau == 118) { tk.sh = 5; tk.c16 = 0; tk.t_lo = 7; tk.t_hi = 14; tk.jump_s = 0; }             // P=16
    else                 { tk.sh = 6; tk.c16 = 0; tk.t_lo = 0; tk.t_hi = 6;  tk.jump_s = 0; }             // P=8
    return tk;
}

// MFMA layouts (m89-verified convention):
//  A: row = lane&15, k = (lane>>4)*8 + j  |  B: k = (lane>>4)*8 + j, col = lane&15
//  C/D: col = lane&15, row = (lane>>4)*4 + reg
__global__ __launch_bounds__(256, 3)
void afno_mfma(const float* __restrict__ x,
               const float* __restrict__ w1,
               const float* __restrict__ b1,
               const float* __restrict__ w2,
               const float* __restrict__ b2,
               float* __restrict__ out) {
    __shared__ unsigned short xs[8192];     // raw bf16 x, [rows<=256][32]   16 KB
    __shared__ float2 tw[512];              // (cos,sin) of 2*pi*m/512        4 KB
    __shared__ unsigned short tbuf[10240];  // 4 waves x 2 slabs x 1280      20 KB

    int bid = blockIdx.x;
    int w  = bid >> 5;
    int bn = bid & 31;
    int b = bn >> 3, n = bn & 7;

    int tid = threadIdx.x;
    int wv = tid >> 6;
    int lane = tid & 63;
    int lg = lane >> 4;
    int l15 = lane & 15;
    int krow = lg * 8;

    // ---- stage x rows (raw bf16) + twiddles ----
    int rows = 0;
    #pragma unroll
    for (int q = 0; q < 4; ++q) {
        Task t2 = task_params((w << 2) | q);
        rows = rows > (t2.t_hi + 1) ? rows : (t2.t_hi + 1);
    }
    for (int idx = tid; idx < rows * 16; idx += 256) {
        int row = idx >> 4, cp = idx & 15;
        float2 v = *(const float2*)(x + (b * 256 + row) * 256 + n * 32 + cp * 2);
        unsigned int pk = (unsigned int)f2bf(v.x) | ((unsigned int)f2bf(v.y) << 16);
        *(unsigned int*)(xs + idx * 2) = pk;
    }
    for (int m = tid; m < 512; m += 256) {
        float sv, cv;
        sincosf(6.28318530717958647692f * (float)m * (1.0f / 512.0f), &sv, &cv);
        tw[m] = make_float2(cv, sv);
    }

    Task tk = task_params((w << 2) | wv);
    int P = 512 >> tk.sh;
    float invSqrtP = rsqrtf((float)P);

    // ---- weights -> bf16 B-fragments; W1 carries the forward 1/sqrt(P);
    //      negated copies of W11/W21 avoid per-step operand negation ----
    const float* w1r = w1 + n * 1024;
    const float* w1i = w1 + (8 + n) * 1024;
    const float* w2r = w2 + n * 1024;
    const float* w2i = w2 + (8 + n) * 1024;
    short8v W10[2], W11[2], W11n[2], W20[2], W21[2], W21n[2];
    float b1r_[2], b1i_[2], b2r_[2], b2i_[2];
    #pragma unroll
    for (int h = 0; h < 2; ++h) {
        int col = h * 16 + l15;
        #pragma unroll
        for (int j = 0; j < 8; ++j) {
            W10[h][j]  = (short)f2bf(w1r[(krow + j) * 32 + col] * invSqrtP);
            W11[h][j]  = (short)f2bf(w1i[(krow + j) * 32 + col] * invSqrtP);
            W11n[h][j] = W11[h][j] ^ (short)0x8000;
            W20[h][j]  = (short)f2bf(w2r[(krow + j) * 32 + col]);
            W21[h][j]  = (short)f2bf(w2i[(krow + j) * 32 + col]);
            W21n[h][j] = W21[h][j] ^ (short)0x8000;
        }
        b1r_[h] = b1[n * 32 + col];
        b1i_[h] = b1[(8 + n) * 32 + col];
        b2r_[h] = b2[n * 32 + col];
        b2i_[h] = b2[(8 + n) * 32 + col];
    }
    __syncthreads();   // only block barrier

    int cbase = tk.c16 * 16;
    int pA5 = ((cbase + l15) << tk.sh) & 511;
    int prow5[4];
    #pragma unroll
    for (int r = 0; r < 4; ++r) prow5[r] = ((cbase + lg * 4 + r) << tk.sh) & 511;

    unsigned short* slab0 = tbuf + wv * 2560;   // [R:16x40][I:16x40]
    unsigned short* slab1 = slab0 + 1280;
    int prl = ((l15 & 3) << 2) | (l15 >> 2);    // row involution (bank spread)

    float Xre[8] = {0,0,0,0,0,0,0,0}, Xim[8] = {0,0,0,0,0,0,0,0};
    int mA5 = 0;
    bool jumped = tk.jump_s > 0;

    if (jumped) {
        // ---- prefix jump: X = sum_{s<jump_s} e^{-i th} x[s] via MFMA ----
        f32x4 jre0 = {0,0,0,0}, jre1 = {0,0,0,0}, jim0 = {0,0,0,0}, jim1 = {0,0,0,0};
        int nkk = tk.jump_s >> 5;
        for (int kk = 0; kk < nkk; ++kk) {
            int sb = kk * 32;
            int mj = (pA5 * (sb + krow)) & 511;
            short8v ac, an_;
            #pragma unroll
            for (int j = 0; j < 8; ++j) {
                float2 t = tw[mj];
                mj = (mj + pA5) & 511;
                ac[j]  = (short)f2bf(t.x);
                an_[j] = (short)f2bf(-t.y);
            }
            short8v bx0, bx1;
            #pragma unroll
            for (int j = 0; j < 8; ++j) {
                int base = (sb + krow + j) * 32 + l15;
                bx0[j] = (short)xs[base];
                bx1[j] = (short)xs[base + 16];
            }
            jre0 = MFMA(BF(ac),  BF(bx0), jre0, 0, 0, 0);
            jim0 = MFMA(BF(an_), BF(bx0), jim0, 0, 0, 0);
            jre1 = MFMA(BF(ac),  BF(bx1), jre1, 0, 0, 0);
            jim1 = MFMA(BF(an_), BF(bx1), jim1, 0, 0, 0);
        }
        // C->A transpose through slabs (f32 [16][33] = 2112 B per slab)
        float* jtR = (float*)slab0;
        float* jtI = (float*)slab1;
        #pragma unroll
        for (int r = 0; r < 4; ++r) {
            jtR[(lg * 4 + r) * 33 + l15]      = jre0[r];
            jtR[(lg * 4 + r) * 33 + 16 + l15] = jre1[r];
            jtI[(lg * 4 + r) * 33 + l15]      = jim0[r];
            jtI[(lg * 4 + r) * 33 + 16 + l15] = jim1[r];
        }
        LDS_FENCE();
        #pragma unroll
        for (int j = 0; j < 8; ++j) {
            Xre[j] = jtR[l15 * 33 + krow + j];
            Xim[j] = jtI[l15 * 33 + krow + j];
        }
        LDS_FENCE();
        mA5 = (pA5 * tk.jump_s) & 511;
    } else {
        // small-P incremental prefix (<=15 steps)
        for (int s = 0; s < tk.t_lo; ++s) {
            float2 tA = tw[mA5];
            mA5 = (mA5 + pA5) & 511;
            short8v xv8 = *(const short8v*)(xs + s * 32 + krow);
            #pragma unroll
            for (int j = 0; j < 8; ++j) {
                float xf = bf2f((unsigned short)xv8[j]);
                Xre[j] = fmaf(xf, tA.x, Xre[j]);
                Xim[j] = fmaf(xf, -tA.y, Xim[j]);
            }
        }
    }

    int mrow5[4];
    #pragma unroll
    for (int r = 0; r < 4; ++r) mrow5[r] = (prow5[r] * tk.t_lo) & 511;

    // ---- helpers as macros over compile-time q ----
#define UPDATE_X(sidx)  do { \
        float2 tA = tw[mA5]; \
        mA5 = (mA5 + pA5) & 511; \
        short8v xv8 = *(const short8v*)(xs + (sidx) * 32 + krow); \
        _Pragma("unroll") \
        for (int j = 0; j < 8; ++j) { \
            float xf = bf2f((unsigned short)xv8[j]); \
            Xre[j] = fmaf(xf, tA.x, Xre[j]); \
            Xim[j] = fmaf(xf, -tA.y, Xim[j]); \
        } } while (0)

#define CVT_A(q)  do { \
        _Pragma("unroll") \
        for (int j = 0; j < 8; ++j) { \
            ar[q][j] = (short)f2bf(Xre[j]); \
            ai[q][j] = (short)f2bf(Xim[j]); \
        } } while (0)

#define LAYER1(q)  do { \
        _Pragma("unroll") \
        for (int h = 0; h < 2; ++h) { \
            f32x4 cr = {b1r_[h], b1r_[h], b1r_[h], b1r_[h]}; \
            f32x4 ci = {b1i_[h], b1i_[h], b1i_[h], b1i_[h]}; \
            o1r[q][h] = MFMA(BF(ar[q]), BF(W10[h]), cr, 0, 0, 0); \
            o1r[q][h] = MFMA(BF(ai[q]), BF(W11n[h]), o1r[q][h], 0, 0, 0); \
            o1i[q][h] = MFMA(BF(ai[q]), BF(W10[h]), ci, 0, 0, 0); \
            o1i[q][h] = MFMA(BF(ar[q]), BF(W11[h]), o1i[q][h], 0, 0, 0); \
        } } while (0)

#define WRITE_T(q, sl)  do { \
        _Pragma("unroll") \
        for (int h = 0; h < 2; ++h) \
            _Pragma("unroll") \
            for (int r = 0; r < 4; ++r) { \
                (sl)[(r * 4 + lg) * 40 + h * 16 + l15]       = f2bf(fmaxf(o1r[q][h][r], 0.f)); \
                (sl)[640 + (r * 4 + lg) * 40 + h * 16 + l15] = f2bf(fmaxf(o1i[q][h][r], 0.f)); \
            } } while (0)

#define READ_T(q, sl)  do { \
        a2r[q] = *(const short8v*)((sl) + prl * 40 + krow); \
        a2i[q] = *(const short8v*)((sl) + 640 + prl * 40 + krow); \
    } while (0)

#define LAYER2_EPI(q, sidx)  do { \
        f32x4 o2r[2], o2i[2]; \
        _Pragma("unroll") \
        for (int h = 0; h < 2; ++h) { \
            f32x4 cr = {b2r_[h], b2r_[h], b2r_[h], b2r_[h]}; \
            f32x4 ci = {b2i_[h], b2i_[h], b2i_[h], b2i_[h]}; \
            o2r[h] = MFMA(BF(a2r[q]), BF(W20[h]), cr, 0, 0, 0); \
            o2r[h] = MFMA(BF(a2i[q]), BF(W21n[h]), o2r[h], 0, 0, 0); \
            o2i[h] = MFMA(BF(a2i[q]), BF(W20[h]), ci, 0, 0, 0); \
            o2i[h] = MFMA(BF(a2r[q]), BF(W21[h]), o2i[h], 0, 0, 0); \
        } \
        float sh0 = 0.f, sh1 = 0.f; \
        _Pragma("unroll") \
        for (int r = 0; r < 4; ++r) { \
            int mi = (mrow5[r] + (q) * prow5[r]) & 511; \
            float2 tR = tw[mi]; \
            float v0r = o2r[0][r]; v0r -= __builtin_amdgcn_fmed3f(v0r, -LAM, LAM); \
            float v0i = o2i[0][r]; v0i -= __builtin_amdgcn_fmed3f(v0i, -LAM, LAM); \
            sh0 = fmaf(v0r, tR.x, sh0); sh0 = fmaf(-v0i, tR.y, sh0); \
            float v1r = o2r[1][r]; v1r -= __builtin_amdgcn_fmed3f(v1r, -LAM, LAM); \
            float v1i = o2i[1][r]; v1i -= __builtin_amdgcn_fmed3f(v1i, -LAM, LAM); \
            sh1 = fmaf(v1r, tR.x, sh1); sh1 = fmaf(-v1i, tR.y, sh1); \
        } \
        sh0 += __shfl_xor(sh0, 16); \
        sh1 += __shfl_xor(sh1, 16); \
        if (P > 8) { sh0 += __shfl_xor(sh0, 32); sh1 += __shfl_xor(sh1, 32); } \
        float vsel = (lane & 16) ? sh1 : sh0; \
        if (lane < 32) \
            atomicAdd(out + (b * 256 + (sidx)) * 256 + n * 32 + (lane & 31), vsel * invSqrtP); \
    } while (0)

    int s = tk.t_lo;
    bool first = true;
    while (s + 3 <= tk.t_hi) {
        short8v ar[4], ai[4], a2r[4], a2i[4];
        f32x4 o1r[4][2], o1i[4][2];
        if (!(jumped && first)) UPDATE_X(s);
        CVT_A(0);
        UPDATE_X(s + 1); CVT_A(1);
        UPDATE_X(s + 2); CVT_A(2);
        UPDATE_X(s + 3); CVT_A(3);
        LAYER1(0); LAYER1(1); LAYER1(2); LAYER1(3);
        LDS_FENCE();                 // WAR: prev iter's slab reads complete
        WRITE_T(0, slab0); WRITE_T(1, slab1);
        LDS_FENCE();
        READ_T(0, slab0); READ_T(1, slab1);
        LDS_FENCE();                 // reads returned; slabs reusable
        WRITE_T(2, slab0); WRITE_T(3, slab1);
        LDS_FENCE();
        READ_T(2, slab0); READ_T(3, slab1);
        LAYER2_EPI(0, s); LAYER2_EPI(1, s + 1);
        LAYER2_EPI(2, s + 2); LAYER2_EPI(3, s + 3);
        #pragma unroll
        for (int r = 0; r < 4; ++r) mrow5[r] = (mrow5[r] + 4 * prow5[r]) & 511;
        first = false; s += 4;
    }
    while (s <= tk.t_hi) {
        short8v ar[1], ai[1], a2r[1], a2i[1];
        f32x4 o1r[1][2], o1i[1][2];
        if (!(jumped && first)) UPDATE_X(s);
        CVT_A(0);
        LAYER1(0);
        LDS_FENCE();
        WRITE_T(0, slab0);
        LDS_FENCE();
        READ_T(0, slab0);
        LAYER2_EPI(0, s);
        #pragma unroll
        for (int r = 0; r < 4; ++r) mrow5[r] = (mrow5[r] + prow5[r]) & 511;
        first = false; s += 1;
    }
}

extern "C" void kernel_launch(void* const* d_in, const int* in_sizes, int n_in,
                              void* d_out, int out_size, void* d_ws, size_t ws_size,
                              hipStream_t stream) {
    const float* x  = (const float*)d_in[0];
    const float* w1 = (const float*)d_in[1];
    const float* b1 = (const float*)d_in[2];
    const float* w2 = (const float*)d_in[3];
    const float* b2 = (const float*)d_in[4];
    float* out = (float*)d_out;

    // out = x (the "+ x" residual), then the main kernel atomically accumulates.
    hipMemcpyAsync(out, x, (size_t)(4 * 256 * 256) * sizeof(float),
                   hipMemcpyDeviceToDevice, stream);
    hipLaunchKernelGGL(afno_mfma, dim3(960), dim3(256), 0, stream,
                       x, w1, b1, w2, b2, out);
}

// Round 9
// 67.853 us; speedup vs baseline: 1.6274x; 1.4380x over previous
//
#include <hip/hip_runtime.h>
#include <math.h>

#define LAM 0.01f

typedef __bf16 bf16x8 __attribute__((ext_vector_type(8)));
typedef float f32x4 __attribute__((ext_vector_type(4)));
typedef short short8v __attribute__((ext_vector_type(8)));
typedef unsigned int uint4v __attribute__((ext_vector_type(4)));

#define BF(v) __builtin_bit_cast(bf16x8, (v))
#define MFMA __builtin_amdgcn_mfma_f32_16x16x32_bf16
#define LDS_FENCE() do { asm volatile("s_waitcnt lgkmcnt(0)" ::: "memory"); \
                         __builtin_amdgcn_sched_barrier(0); } while (0)

__device__ __forceinline__ unsigned short f2bf(float f) {
    __bf16 h = (__bf16)f;
    return __builtin_bit_cast(unsigned short, h);
}
__device__ __forceinline__ float bf2f(unsigned short u) {
    unsigned int v = ((unsigned int)u) << 16;
    return __builtin_bit_cast(float, v);
}
__device__ __forceinline__ unsigned int pack2bf(float a, float b) {
    return (unsigned int)f2bf(a) | ((unsigned int)f2bf(b) << 16);
}

// wave task id tau in [0,120): P, chunk-of-16-freqs, t-segment, jump target.
// sh = 9 - log2(P); twiddle indices in 512-space (angle 2*pi*m/512).
struct Task { int sh, c16, t_lo, t_hi, jump_s; };
__device__ __forceinline__ Task task_params(int tau) {
    Task tk;
    if (tau < 64)        { int seg = tau >> 4; tk.sh = 1; tk.c16 = tau & 15;
                           tk.t_lo = 127 + 32 * seg; tk.t_hi = tk.t_lo + 31; tk.jump_s = tk.t_lo + 1; }  // P=256
    else if (tau < 96)   { tk.sh = 0; tk.c16 = tau - 64; tk.t_lo = 255; tk.t_hi = 255; tk.jump_s = 256; } // P=512
    else if (tau < 112)  { int u = tau - 96; int seg = u >> 3; tk.sh = 2; tk.c16 = u & 7;
                           tk.t_lo = 63 + 32 * seg; tk.t_hi = tk.t_lo + 31; tk.jump_s = tk.t_lo + 1; }    // P=128
    else if (tau < 116)  { tk.sh = 3; tk.c16 = tau - 112; tk.t_lo = 31; tk.t_hi = 62; tk.jump_s = 32; }   // P=64
    else if (tau < 118)  { tk.sh = 4; tk.c16 = tau - 116; tk.t_lo = 15; tk.t_hi = 30; tk.jump_s = 0; }    // P=32
    else if (tau == 118) { tk.sh = 5; tk.c16 = 0; tk.t_lo = 7; tk.t_hi = 14; tk.jump_s = 0; }             // P=16
    else                 { tk.sh = 6; tk.c16 = 0; tk.t_lo = 0; tk.t_hi = 6;  tk.jump_s = 0; }             // P=8
    return tk;
}

// MFMA layouts (m89-verified): arg0 row=lane&15, k=(lane>>4)*8+j;
// arg1 k=(lane>>4)*8+j, col=lane&15; C/D col=lane&15, row=(lane>>4)*4+reg.
// Layer 1 computed TRANSPOSED (o1^T = W1^T * X^T): arg0 = W1-frag,
// arg1 = X-frag (same register contents as the untransposed version).
// C1 -> layer2-A relayout moves data only across 16-lane groups at fixed
// lane&15 -> pure-register shfl, no LDS on the per-step path.
__global__ __launch_bounds__(256, 3)
void afno_mfma(const float* __restrict__ x,
               const float* __restrict__ w1,
               const float* __restrict__ b1,
               const float* __restrict__ w2,
               const float* __restrict__ b2,
               float* __restrict__ out) {
    __shared__ unsigned short xs[8192];   // raw bf16 x, [rows<=256][32]  16 KB
    __shared__ float twc[544];            // cos(2*pi*m/512), idx m+(m>>4)
    __shared__ float tws[544];            // sin
    __shared__ float jslab[4 * 544];      // per-wave f32 [16][33] jump slab

    int bid = blockIdx.x;
    int w  = bid >> 5;
    int bn = bid & 31;
    int b = bn >> 3, n = bn & 7;

    int tid = threadIdx.x;
    int wv = tid >> 6;
    int lane = tid & 63;
    int lg = lane >> 4;
    int l15 = lane & 15;
    int krow = lg * 8;

    // ---- stage x rows (raw bf16) + twiddles ----
    int rows = 0;
    #pragma unroll
    for (int q = 0; q < 4; ++q) {
        Task t2 = task_params((w << 2) | q);
        rows = rows > (t2.t_hi + 1) ? rows : (t2.t_hi + 1);
    }
    for (int idx = tid; idx < rows * 16; idx += 256) {
        int row = idx >> 4, cp = idx & 15;
        float2 v = *(const float2*)(x + (b * 256 + row) * 256 + n * 32 + cp * 2);
        unsigned int pk = (unsigned int)f2bf(v.x) | ((unsigned int)f2bf(v.y) << 16);
        *(unsigned int*)(xs + idx * 2) = pk;
    }
    for (int m = tid; m < 512; m += 256) {
        float sv, cv;
        sincosf(6.28318530717958647692f * (float)m * (1.0f / 512.0f), &sv, &cv);
        twc[m + (m >> 4)] = cv;
        tws[m + (m >> 4)] = sv;
    }

    Task tk = task_params((w << 2) | wv);
    int P = 512 >> tk.sh;
    float invSqrtP = rsqrtf((float)P);

    // ---- weights -> bf16 fragments; W1 carries 1/sqrt(P) ----
    const float* w1r = w1 + n * 1024;
    const float* w1i = w1 + (8 + n) * 1024;
    const float* w2r = w2 + n * 1024;
    const float* w2i = w2 + (8 + n) * 1024;
    short8v W10[2], W11[2], W11n[2], W20[2], W21[2], W21n[2];
    #pragma unroll
    for (int h = 0; h < 2; ++h) {
        int col = h * 16 + l15;
        #pragma unroll
        for (int j = 0; j < 8; ++j) {
            W10[h][j]  = (short)f2bf(w1r[(krow + j) * 32 + col] * invSqrtP);
            W11[h][j]  = (short)f2bf(w1i[(krow + j) * 32 + col] * invSqrtP);
            W11n[h][j] = W11[h][j] ^ (short)0x8000;
            W20[h][j]  = (short)f2bf(w2r[(krow + j) * 32 + col]);
            W21[h][j]  = (short)f2bf(w2i[(krow + j) * 32 + col]);
            W21n[h][j] = W21[h][j] ^ (short)0x8000;
        }
    }
    // layer1 bias per C1-ROW (o = h*16 + lg*4 + r); layer2 bias per col.
    f32x4 b1rv[2], b1iv[2];
    float b2r_[2], b2i_[2];
    #pragma unroll
    for (int h = 0; h < 2; ++h) {
        int base = n * 32 + h * 16 + lg * 4;
        b1rv[h] = f32x4{b1[base], b1[base + 1], b1[base + 2], b1[base + 3]};
        b1iv[h] = f32x4{b1[256 + base], b1[256 + base + 1], b1[256 + base + 2], b1[256 + base + 3]};
        b2r_[h] = b2[n * 32 + h * 16 + l15];
        b2i_[h] = b2[256 + n * 32 + h * 16 + l15];
    }
    __syncthreads();   // only block barrier

    int cbase = tk.c16 * 16;
    int pA5 = ((cbase + l15) << tk.sh) & 511;
    int prow5[4];
    #pragma unroll
    for (int r = 0; r < 4; ++r) prow5[r] = ((cbase + lg * 4 + r) << tk.sh) & 511;

    int idxa = ((lg & 1) << 5) + l15;   // source lane for j=0..3 (group 2*(lg&1))
    int idxb = idxa + 16;               // source lane for j=4..7
    bool hsel = (lg >= 2);              // which C1-half feeds this lane group

    float Xre[8] = {0,0,0,0,0,0,0,0}, Xim[8] = {0,0,0,0,0,0,0,0};
    int mA5 = 0;
    bool jumped = tk.jump_s > 0;

    if (jumped) {
        // ---- prefix jump: X = sum_{s<jump_s} e^{-i th} x[s] via MFMA ----
        f32x4 jre0 = {0,0,0,0}, jre1 = {0,0,0,0}, jim0 = {0,0,0,0}, jim1 = {0,0,0,0};
        int nkk = tk.jump_s >> 5;
        for (int kk = 0; kk < nkk; ++kk) {
            int sb = kk * 32;
            int mj = (pA5 * (sb + krow)) & 511;
            short8v ac, an_;
            #pragma unroll
            for (int j = 0; j < 8; ++j) {
                int mi_ = mj + (mj >> 4);
                float tc_ = twc[mi_], tsn_ = tws[mi_];
                mj = (mj + pA5) & 511;
                ac[j]  = (short)f2bf(tc_);
                an_[j] = (short)f2bf(-tsn_);
            }
            short8v bx0, bx1;
            #pragma unroll
            for (int j = 0; j < 8; ++j) {
                int base = (sb + krow + j) * 32 + l15;
                bx0[j] = (short)xs[base];
                bx1[j] = (short)xs[base + 16];
            }
            jre0 = MFMA(BF(ac),  BF(bx0), jre0, 0, 0, 0);
            jim0 = MFMA(BF(an_), BF(bx0), jim0, 0, 0, 0);
            jre1 = MFMA(BF(ac),  BF(bx1), jre1, 0, 0, 0);
            jim1 = MFMA(BF(an_), BF(bx1), jim1, 0, 0, 0);
        }
        // C->A transpose through per-wave f32 slab (twice: re, im)
        float* jt = jslab + wv * 544;
        #pragma unroll
        for (int r = 0; r < 4; ++r) {
            jt[(lg * 4 + r) * 33 + l15]      = jre0[r];
            jt[(lg * 4 + r) * 33 + 16 + l15] = jre1[r];
        }
        LDS_FENCE();
        #pragma unroll
        for (int j = 0; j < 8; ++j) Xre[j] = jt[l15 * 33 + krow + j];
        LDS_FENCE();
        #pragma unroll
        for (int r = 0; r < 4; ++r) {
            jt[(lg * 4 + r) * 33 + l15]      = jim0[r];
            jt[(lg * 4 + r) * 33 + 16 + l15] = jim1[r];
        }
        LDS_FENCE();
        #pragma unroll
        for (int j = 0; j < 8; ++j) Xim[j] = jt[l15 * 33 + krow + j];
        LDS_FENCE();
        mA5 = (pA5 * tk.jump_s) & 511;
    } else {
        // small-P incremental prefix (<=15 steps)
        for (int s = 0; s < tk.t_lo; ++s) {
            int mi_ = mA5 + (mA5 >> 4);
            float tc_ = twc[mi_], tsn_ = tws[mi_];
            mA5 = (mA5 + pA5) & 511;
            short8v xv8 = *(const short8v*)(xs + s * 32 + krow);
            #pragma unroll
            for (int j = 0; j < 8; ++j) {
                float xf = bf2f((unsigned short)xv8[j]);
                Xre[j] = fmaf(xf, tc_, Xre[j]);
                Xim[j] = fmaf(xf, -tsn_, Xim[j]);
            }
        }
    }

    int mrow5[4];
    #pragma unroll
    for (int r = 0; r < 4; ++r) mrow5[r] = (prow5[r] * tk.t_lo) & 511;

#define UPDATE_X(sidx) do { \
        int mi_ = mA5 + (mA5 >> 4); \
        float tc_ = twc[mi_], tsn_ = tws[mi_]; \
        mA5 = (mA5 + pA5) & 511; \
        short8v xv8 = *(const short8v*)(xs + (sidx) * 32 + krow); \
        _Pragma("unroll") \
        for (int j = 0; j < 8; ++j) { \
            float xf = bf2f((unsigned short)xv8[j]); \
            Xre[j] = fmaf(xf, tc_, Xre[j]); \
            Xim[j] = fmaf(xf, -tsn_, Xim[j]); \
        } } while (0)

#define DO_STEP(sidx, do_upd) do { \
        if (do_upd) UPDATE_X(sidx); \
        short8v ar_, ai_; \
        _Pragma("unroll") \
        for (int j = 0; j < 8; ++j) { \
            ar_[j] = (short)f2bf(Xre[j]); \
            ai_[j] = (short)f2bf(Xim[j]); \
        } \
        /* layer 1 transposed: C1[o&15, p], h = o-half */ \
        f32x4 o1r_[2], o1i_[2]; \
        _Pragma("unroll") \
        for (int h = 0; h < 2; ++h) { \
            o1r_[h] = MFMA(BF(W10[h]),  BF(ar_), b1rv[h], 0, 0, 0); \
            o1r_[h] = MFMA(BF(W11n[h]), BF(ai_), o1r_[h], 0, 0, 0); \
            o1i_[h] = MFMA(BF(W10[h]),  BF(ai_), b1iv[h], 0, 0, 0); \
            o1i_[h] = MFMA(BF(W11[h]),  BF(ar_), o1i_[h], 0, 0, 0); \
        } \
        /* relu + pack regs (0,1)/(2,3) to dwords */ \
        unsigned int pr00 = pack2bf(fmaxf(o1r_[0][0], 0.f), fmaxf(o1r_[0][1], 0.f)); \
        unsigned int pr01 = pack2bf(fmaxf(o1r_[0][2], 0.f), fmaxf(o1r_[0][3], 0.f)); \
        unsigned int pr10 = pack2bf(fmaxf(o1r_[1][0], 0.f), fmaxf(o1r_[1][1], 0.f)); \
        unsigned int pr11 = pack2bf(fmaxf(o1r_[1][2], 0.f), fmaxf(o1r_[1][3], 0.f)); \
        unsigned int pi00 = pack2bf(fmaxf(o1i_[0][0], 0.f), fmaxf(o1i_[0][1], 0.f)); \
        unsigned int pi01 = pack2bf(fmaxf(o1i_[0][2], 0.f), fmaxf(o1i_[0][3], 0.f)); \
        unsigned int pi10 = pack2bf(fmaxf(o1i_[1][0], 0.f), fmaxf(o1i_[1][1], 0.f)); \
        unsigned int pi11 = pack2bf(fmaxf(o1i_[1][2], 0.f), fmaxf(o1i_[1][3], 0.f)); \
        /* cross-group regroup: layer2 A-frag via register shfl */ \
        uint4v u_r, u_i; \
        { unsigned int sa_, sb_; \
          sa_ = (unsigned int)__shfl((int)pr00, idxa); sb_ = (unsigned int)__shfl((int)pr10, idxa); u_r.x = hsel ? sb_ : sa_; \
          sa_ = (unsigned int)__shfl((int)pr01, idxa); sb_ = (unsigned int)__shfl((int)pr11, idxa); u_r.y = hsel ? sb_ : sa_; \
          sa_ = (unsigned int)__shfl((int)pr00, idxb); sb_ = (unsigned int)__shfl((int)pr10, idxb); u_r.z = hsel ? sb_ : sa_; \
          sa_ = (unsigned int)__shfl((int)pr01, idxb); sb_ = (unsigned int)__shfl((int)pr11, idxb); u_r.w = hsel ? sb_ : sa_; \
          sa_ = (unsigned int)__shfl((int)pi00, idxa); sb_ = (unsigned int)__shfl((int)pi10, idxa); u_i.x = hsel ? sb_ : sa_; \
          sa_ = (unsigned int)__shfl((int)pi01, idxa); sb_ = (unsigned int)__shfl((int)pi11, idxa); u_i.y = hsel ? sb_ : sa_; \
          sa_ = (unsigned int)__shfl((int)pi00, idxb); sb_ = (unsigned int)__shfl((int)pi10, idxb); u_i.z = hsel ? sb_ : sa_; \
          sa_ = (unsigned int)__shfl((int)pi01, idxb); sb_ = (unsigned int)__shfl((int)pi11, idxb); u_i.w = hsel ? sb_ : sa_; } \
        short8v a2r_ = __builtin_bit_cast(short8v, u_r); \
        short8v a2i_ = __builtin_bit_cast(short8v, u_i); \
        /* layer 2 (standard orientation) */ \
        f32x4 o2r_[2], o2i_[2]; \
        _Pragma("unroll") \
        for (int h = 0; h < 2; ++h) { \
            f32x4 cr = {b2r_[h], b2r_[h], b2r_[h], b2r_[h]}; \
            f32x4 ci = {b2i_[h], b2i_[h], b2i_[h], b2i_[h]}; \
            o2r_[h] = MFMA(BF(a2r_), BF(W20[h]), cr, 0, 0, 0); \
            o2r_[h] = MFMA(BF(a2i_), BF(W21n[h]), o2r_[h], 0, 0, 0); \
            o2i_[h] = MFMA(BF(a2i_), BF(W20[h]), ci, 0, 0, 0); \
            o2i_[h] = MFMA(BF(a2r_), BF(W21[h]), o2i_[h], 0, 0, 0); \
        } \
        /* softshrink + inverse twiddle + p-row reduce + atomic */ \
        float sh0 = 0.f, sh1 = 0.f; \
        _Pragma("unroll") \
        for (int r = 0; r < 4; ++r) { \
            int mi_ = mrow5[r] + (mrow5[r] >> 4); \
            float tc_ = twc[mi_], tsn_ = tws[mi_]; \
            mrow5[r] = (mrow5[r] + prow5[r]) & 511; \
            float v0r = o2r_[0][r]; v0r -= __builtin_amdgcn_fmed3f(v0r, -LAM, LAM); \
            float v0i = o2i_[0][r]; v0i -= __builtin_amdgcn_fmed3f(v0i, -LAM, LAM); \
            sh0 = fmaf(v0r, tc_, sh0); sh0 = fmaf(-v0i, tsn_, sh0); \
            float v1r = o2r_[1][r]; v1r -= __builtin_amdgcn_fmed3f(v1r, -LAM, LAM); \
            float v1i = o2i_[1][r]; v1i -= __builtin_amdgcn_fmed3f(v1i, -LAM, LAM); \
            sh1 = fmaf(v1r, tc_, sh1); sh1 = fmaf(-v1i, tsn_, sh1); \
        } \
        sh0 += __shfl_xor(sh0, 16); \
        sh1 += __shfl_xor(sh1, 16); \
        if (P > 8) { sh0 += __shfl_xor(sh0, 32); sh1 += __shfl_xor(sh1, 32); } \
        float vsel = (lane & 16) ? sh1 : sh0; \
        if (lane < 32) \
            atomicAdd(out + (b * 256 + (sidx)) * 256 + n * 32 + (lane & 31), vsel * invSqrtP); \
    } while (0)

    int s = tk.t_lo;
    bool skip0 = jumped;
    while (s + 1 <= tk.t_hi) {
        DO_STEP(s, !skip0);
        DO_STEP(s + 1, true);
        skip0 = false;
        s += 2;
    }
    if (s <= tk.t_hi) {
        DO_STEP(s, !skip0);
    }
}

extern "C" void kernel_launch(void* const* d_in, const int* in_sizes, int n_in,
                              void* d_out, int out_size, void* d_ws, size_t ws_size,
                              hipStream_t stream) {
    const float* x  = (const float*)d_in[0];
    const float* w1 = (const float*)d_in[1];
    const float* b1 = (const float*)d_in[2];
    const float* w2 = (const float*)d_in[3];
    const float* b2 = (const float*)d_in[4];
    float* out = (float*)d_out;

    // out = x (the "+ x" residual), then the main kernel atomically accumulates.
    hipMemcpyAsync(out, x, (size_t)(4 * 256 * 256) * sizeof(float),
                   hipMemcpyDeviceToDevice, stream);
    hipLaunchKernelGGL(afno_mfma, dim3(960), dim3(256), 0, stream,
                       x, w1, b1, w2, b2, out);
}